// Round 1
// baseline (672.882 us; speedup 1.0000x reference)
//
#include <hip/hip_runtime.h>
#include <hip/hip_bf16.h>

#define NE   8
#define DIN  2048
#define DOUT 8192
#define NTOK 8192

typedef __bf16 bf16;
typedef __attribute__((ext_vector_type(8))) __bf16 bf16x8;
typedef __attribute__((ext_vector_type(4))) float f32x4;

// round-to-nearest-even f32 -> bf16 (finite inputs)
__device__ inline bf16 f2bf(float x) {
  union { float f; unsigned u; } v; v.f = x;
  unsigned r = v.u + 0x7fffu + ((v.u >> 16) & 1u);
  union { unsigned short s; bf16 b; } o; o.s = (unsigned short)(r >> 16);
  return o.b;
}

// expert_size may arrive as int64 (reference) or int32 (harness doc says int).
// EXPERT_SIZES[1] = 1536 != 0, so the second int32 word disambiguates.
__device__ inline int find_expert(const void* esv, int mrow) {
  const int* p32 = (const int*)esv;
  const long long* p64 = (const long long*)esv;
  bool is64 = (p32[1] == 0);
  long long cum = 0; int e = 0;
  #pragma unroll
  for (int i = 0; i < NE; ++i) {
    long long s = is64 ? p64[i] : (long long)p32[i];
    long long nx = cum + s;
    if ((long long)mrow >= nx) e = i + 1;
    cum = nx;
  }
  return e;
}

// ---------------- pass 1a: A fp32 -> bf16 (same layout) ----------------
__global__ __launch_bounds__(256) void convertA(const float* __restrict__ A,
                                                bf16* __restrict__ Ab) {
  size_t i = ((size_t)blockIdx.x * 256 + threadIdx.x) * 8;
  float4 a = *(const float4*)(A + i);
  float4 b = *(const float4*)(A + i + 4);
  const float* f = (const float*)&a;
  const float* g = (const float*)&b;
  bf16x8 v;
  #pragma unroll
  for (int j = 0; j < 4; ++j) { v[j] = f2bf(f[j]); v[4 + j] = f2bf(g[j]); }
  *(bf16x8*)(Ab + i) = v;
}

// ------- pass 1b: W [E][K][N] fp32 -> BT [E][N][K] bf16 (transpose) -------
__global__ __launch_bounds__(256) void convertB(const float* __restrict__ W,
                                                bf16* __restrict__ BT) {
  __shared__ bf16 tile[64][72];  // [k_local][n_local], pad to 144B stride
  const int e  = blockIdx.z;
  const int n0 = blockIdx.x * 64;
  const int k0 = blockIdx.y * 64;
  const int t  = threadIdx.x;
  const int tr = t >> 2;          // 0..63
  const int tc = (t & 3) << 4;    // 0,16,32,48

  // load phase: tr = local k row, tc.. = local n cols (coalesced fp32 reads)
  const float* src = W + ((size_t)e * DIN + k0 + tr) * DOUT + n0 + tc;
  #pragma unroll
  for (int i = 0; i < 4; ++i) {
    float4 v = *(const float4*)(src + 4 * i);
    const float* f = (const float*)&v;
    #pragma unroll
    for (int j = 0; j < 4; ++j) tile[tr][tc + 4 * i + j] = f2bf(f[j]);
  }
  __syncthreads();

  // write phase: tr = local n row, tc.. = local k cols (coalesced bf16 writes)
  bf16x8 v0, v1;
  #pragma unroll
  for (int j = 0; j < 8; ++j) { v0[j] = tile[tc + j][tr]; v1[j] = tile[tc + 8 + j][tr]; }
  bf16* dst = BT + ((size_t)e * DOUT + n0 + tr) * DIN + k0 + tc;
  *(bf16x8*)dst = v0;
  *(bf16x8*)(dst + 8) = v1;
}

// ---------------- pass 2: grouped GEMM, m97 structure ----------------
// C[m][n] = sum_k A[m][k] * BT[e][n][k], tiles 128x128, BK=64, 4 waves
#define BM 128
#define BN 128
#define BK 64

#define GLOAD(g, l) __builtin_amdgcn_global_load_lds(                      \
    (const __attribute__((address_space(1))) void*)(g),                    \
    (__attribute__((address_space(3))) void*)(l), 16, 0, 0)

__global__ __launch_bounds__(256) void grouped_gemm(
    const bf16* __restrict__ A, const bf16* __restrict__ BT,
    const void* __restrict__ es, float* __restrict__ C) {
  __shared__ bf16 As[BM * BK];
  __shared__ bf16 Bs[BN * BK];

  // XCD-bijective swizzle: 4096 blocks, 8 XCDs, 512 per chunk
  const int bid = blockIdx.x;
  const int wid = (bid & 7) * 512 + (bid >> 3);
  const int mtile = wid >> 6;   // 64 ntiles
  const int ntile = wid & 63;
  const int mrow = mtile * BM;
  const int ncol = ntile * BN;
  const int e = find_expert(es, mrow);

  const int t    = threadIdx.x;
  const int lane = t & 63;
  const int wr   = ((t >> 6) >> 1) * 64;   // wave row offset (0/64)
  const int wc   = ((t >> 6) & 1) * 64;    // wave col offset (0/64)

  const int srow = t >> 3;        // staging row 0..31
  const int scol = (t & 7) * 8;   // staging col 0..56

  const bf16* Abase = A + (size_t)mrow * DIN;
  const bf16* Bbase = BT + (size_t)e * DOUT * DIN + (size_t)ncol * DIN;

  f32x4 acc[4][4];
  #pragma unroll
  for (int m = 0; m < 4; ++m)
    #pragma unroll
    for (int n = 0; n < 4; ++n) acc[m][n] = (f32x4){0.f, 0.f, 0.f, 0.f};

  const int l15 = lane & 15;
  const int kg  = (lane >> 4) * 8;

  for (int kt = 0; kt < DIN / BK; ++kt) {
    const int kb = kt * BK;
    #pragma unroll
    for (int i = 0; i < 4; ++i) {
      const int r = i * 32 + srow;
      GLOAD(Abase + (size_t)r * DIN + kb + scol, &As[r * BK + scol]);
      GLOAD(Bbase + (size_t)r * DIN + kb + scol, &Bs[r * BK + scol]);
    }
    __syncthreads();   // compiler drains vmcnt before s_barrier

    #pragma unroll
    for (int kk = 0; kk < 2; ++kk) {
      const int ko = kk * 32 + kg;
      bf16x8 af[4], bfr[4];
      #pragma unroll
      for (int m = 0; m < 4; ++m)
        af[m] = *(const bf16x8*)&As[(wr + m * 16 + l15) * BK + ko];
      #pragma unroll
      for (int n = 0; n < 4; ++n)
        bfr[n] = *(const bf16x8*)&Bs[(wc + n * 16 + l15) * BK + ko];
      #pragma unroll
      for (int m = 0; m < 4; ++m)
        #pragma unroll
        for (int n = 0; n < 4; ++n)
          acc[m][n] = __builtin_amdgcn_mfma_f32_16x16x32_bf16(
              af[m], bfr[n], acc[m][n], 0, 0, 0);
    }
    __syncthreads();
  }

  // C/D layout: col = lane&15, row = (lane>>4)*4 + reg
  float* Cb = C + (size_t)mrow * DOUT + ncol;
  const int r0 = wr + (lane >> 4) * 4;
  const int c0 = wc + l15;
  #pragma unroll
  for (int m = 0; m < 4; ++m)
    #pragma unroll
    for (int j = 0; j < 4; ++j)
      #pragma unroll
      for (int n = 0; n < 4; ++n)
        Cb[(size_t)(r0 + m * 16 + j) * DOUT + c0 + n * 16] = acc[m][n][j];
}

// ---------------- fallback (ws too small): fp32 tiled GEMM ----------------
__global__ __launch_bounds__(256) void fallback_gemm(
    const float* __restrict__ A, const float* __restrict__ W,
    const void* __restrict__ es, float* __restrict__ C) {
  __shared__ float As[64][17];
  __shared__ float Bs[16][65];
  const int bid = blockIdx.x;
  const int mtile = bid >> 7;          // DOUT/64 = 128 ntiles
  const int ntile = bid & 127;
  const int mrow = mtile * 64, ncol = ntile * 64;
  const int e = find_expert(es, mrow);
  const int t = threadIdx.x;
  const int tx = t & 15, ty = t >> 4;
  float acc[4][4] = {};
  const float* Ab = A + (size_t)mrow * DIN;
  const float* Wb = W + (size_t)e * DIN * DOUT + ncol;
  for (int kb = 0; kb < DIN; kb += 16) {
    {
      const int r = t >> 2, c = (t & 3) * 4;
      float4 v = *(const float4*)(Ab + (size_t)r * DIN + kb + c);
      const float* f = (const float*)&v;
      #pragma unroll
      for (int j = 0; j < 4; ++j) As[r][c + j] = f[j];
      const int r2 = t >> 4, c2 = (t & 15) * 4;
      float4 w = *(const float4*)(Wb + (size_t)(kb + r2) * DOUT + c2);
      const float* g = (const float*)&w;
      #pragma unroll
      for (int j = 0; j < 4; ++j) Bs[r2][c2 + j] = g[j];
    }
    __syncthreads();
    #pragma unroll
    for (int k = 0; k < 16; ++k)
      #pragma unroll
      for (int i = 0; i < 4; ++i)
        #pragma unroll
        for (int j = 0; j < 4; ++j)
          acc[i][j] += As[ty * 4 + i][k] * Bs[k][tx * 4 + j];
    __syncthreads();
  }
  #pragma unroll
  for (int i = 0; i < 4; ++i)
    #pragma unroll
    for (int j = 0; j < 4; ++j)
      C[(size_t)(mrow + ty * 4 + i) * DOUT + ncol + tx * 4 + j] = acc[i][j];
}

extern "C" void kernel_launch(void* const* d_in, const int* in_sizes, int n_in,
                              void* d_out, int out_size, void* d_ws, size_t ws_size,
                              hipStream_t stream) {
  const float* A = (const float*)d_in[0];
  const float* W = (const float*)d_in[1];
  const void*  es = (const void*)d_in[2];
  float* C = (float*)d_out;

  const size_t needA = (size_t)NTOK * DIN * sizeof(bf16);        // 32 MB
  const size_t needB = (size_t)NE * DIN * DOUT * sizeof(bf16);   // 256 MB

  if (ws_size >= needA + needB) {
    bf16* Ab = (bf16*)d_ws;
    bf16* BT = (bf16*)((char*)d_ws + needA);
    convertA<<<(NTOK * DIN) / (256 * 8), 256, 0, stream>>>(A, Ab);
    dim3 gB(DOUT / 64, DIN / 64, NE);
    convertB<<<gB, 256, 0, stream>>>(W, BT);
    grouped_gemm<<<(NTOK / BM) * (DOUT / BN), 256, 0, stream>>>(Ab, BT, es, C);
  } else {
    fallback_gemm<<<(NTOK / 64) * (DOUT / 64), 256, 0, stream>>>(A, W, es, C);
  }
}

// Round 2
// 614.984 us; speedup vs baseline: 1.0941x; 1.0941x over previous
//
#include <hip/hip_runtime.h>
#include <hip/hip_bf16.h>

#define NE   8
#define DIN  2048
#define DOUT 8192
#define NTOK 8192

typedef __bf16 bf16;
typedef __attribute__((ext_vector_type(8))) __bf16 bf16x8;
typedef __attribute__((ext_vector_type(4))) float f32x4;

// round-to-nearest-even f32 -> bf16 (finite inputs)
__device__ __forceinline__ bf16 f2bf(float x) {
  union { float f; unsigned u; } v; v.f = x;
  unsigned r = v.u + 0x7fffu + ((v.u >> 16) & 1u);
  union { unsigned short s; bf16 b; } o; o.s = (unsigned short)(r >> 16);
  return o.b;
}

// ---------------- pass 1a: A fp32 -> bf16 (same layout) ----------------
__global__ __launch_bounds__(256) void convertA(const float* __restrict__ A,
                                                bf16* __restrict__ Ab) {
  size_t i = ((size_t)blockIdx.x * 256 + threadIdx.x) * 8;
  float4 a = *(const float4*)(A + i);
  float4 b = *(const float4*)(A + i + 4);
  const float* f = (const float*)&a;
  const float* g = (const float*)&b;
  bf16x8 v;
  #pragma unroll
  for (int j = 0; j < 4; ++j) { v[j] = f2bf(f[j]); v[4 + j] = f2bf(g[j]); }
  *(bf16x8*)(Ab + i) = v;
}

// ------- pass 1b: W [E][K][N] fp32 -> BT [E][N][K] bf16 (transpose) -------
__global__ __launch_bounds__(256) void convertB(const float* __restrict__ W,
                                                bf16* __restrict__ BT) {
  __shared__ bf16 tile[64][66];  // stride 132B: column reads spread banks
  const int e  = blockIdx.z;
  const int n0 = blockIdx.x * 64;
  const int k0 = blockIdx.y * 64;
  const int t  = threadIdx.x;
  const int tr = t >> 2;          // 0..63
  const int tc = (t & 3) << 4;    // 0,16,32,48

  const float* src = W + ((size_t)e * DIN + k0 + tr) * DOUT + n0 + tc;
  #pragma unroll
  for (int i = 0; i < 4; ++i) {
    float4 v = *(const float4*)(src + 4 * i);
    const float* f = (const float*)&v;
    #pragma unroll
    for (int j = 0; j < 4; ++j) tile[tr][tc + 4 * i + j] = f2bf(f[j]);
  }
  __syncthreads();

  bf16x8 v0, v1;
  #pragma unroll
  for (int j = 0; j < 8; ++j) { v0[j] = tile[tc + j][tr]; v1[j] = tile[tc + 8 + j][tr]; }
  bf16* dst = BT + ((size_t)e * DOUT + n0 + tr) * DIN + k0 + tc;
  *(bf16x8*)dst = v0;
  *(bf16x8*)(dst + 8) = v1;
}

// ---------------- pass 2: grouped GEMM, 256x256 deep-pipelined ----------------
// C[m][n] = sum_k A[m][k] * BT[e][n][k]
// BK=32 -> LDS row stride 64B: fragment ds_read_b128 classes tile the 32 banks
// at the b128 minimum (8 lanes/range) -> no swizzle needed, gload_lds stays linear.
#define BM 256
#define BN 256
#define BK 32
#define TPB 512

#define GL(gp, lp) __builtin_amdgcn_global_load_lds(                        \
    (const __attribute__((address_space(1))) void*)(gp),                    \
    (__attribute__((address_space(3))) void*)(lp), 16, 0, 0)

__global__ __launch_bounds__(TPB, 2) void grouped_gemm(
    const bf16* __restrict__ A, const bf16* __restrict__ BT,
    const void* __restrict__ es, float* __restrict__ C) {
  __shared__ bf16 smem[4 * 2 * BM * BK];  // 4 bufs x (A + B) x 256x32 = 128 KiB

  // XCD-bijective swizzle: 1024 blocks % 8 == 0
  const int bid  = blockIdx.x;
  const int wid  = (bid & 7) * 128 + (bid >> 3);
  const int mrow = (wid >> 5) * BM;
  const int ncol = (wid & 31) * BN;

  // expert offsets (int32 or int64 input)
  const int* p32 = (const int*)es;
  const long long* p64 = (const long long*)es;
  const bool is64 = (p32[1] == 0);
  int offs[NE + 1];
  offs[0] = 0;
  #pragma unroll
  for (int i = 0; i < NE; ++i)
    offs[i + 1] = offs[i] + (int)(is64 ? p64[i] : (long long)p32[i]);
  int e0 = 0, e1 = 0;
  #pragma unroll
  for (int i = 0; i < NE; ++i) {
    if (mrow >= offs[i + 1]) e0 = i + 1;
    if (mrow + BM - 1 >= offs[i + 1]) e1 = i + 1;
  }

  const int t    = threadIdx.x;
  const int lane = t & 63;
  const int w    = t >> 6;
  const int wr   = (w >> 2) * 128;   // wave rows: 0 / 128
  const int wc   = (w & 3) * 64;     // wave cols: 0/64/128/192
  const int l15  = lane & 15;
  const int kg   = lane >> 4;

  // staging: thread t loads 16B; rows r*128 + (t>>2), cols (t&3)*8
  const int srow = t >> 2;
  const int scol = (t & 3) * 8;
  const bf16* Ag = A + (size_t)(mrow + srow) * DIN + scol;
  bf16* Al = smem + srow * BK + scol;   // + buf*(2*BM*BK) [+ 128*BK for round 1]
  bf16* Bl = Al + BM * BK;

  float* Cb = C + (size_t)mrow * DOUT + ncol;

  for (int e = e0; e <= e1; ++e) {
    const bf16* Bg = BT + ((size_t)e * DOUT + ncol + srow) * DIN + scol;

    f32x4 acc[8][4];
    #pragma unroll
    for (int i = 0; i < 8; ++i)
      #pragma unroll
      for (int n = 0; n < 4; ++n) acc[i][n] = (f32x4){0.f, 0.f, 0.f, 0.f};

#define STAGE_A(ST, BUF) do {                                               \
    GL(Ag + (ST) * BK,                     Al + (BUF) * (2 * BM * BK));     \
    GL(Ag + (ST) * BK + (size_t)128 * DIN, Al + (BUF) * (2 * BM * BK) + 128 * BK); } while (0)
#define STAGE_B(ST, BUF) do {                                               \
    GL(Bg + (ST) * BK,                     Bl + (BUF) * (2 * BM * BK));     \
    GL(Bg + (ST) * BK + (size_t)128 * DIN, Bl + (BUF) * (2 * BM * BK) + 128 * BK); } while (0)

    // prologue: K-tiles 0,1,2 -> bufs 0,1,2 (12 gloads/thread)
    #pragma unroll
    for (int pt = 0; pt < 3; ++pt) { STAGE_A(pt, pt); STAGE_B(pt, pt); }
    asm volatile("s_waitcnt vmcnt(8)" ::: "memory");  // tile 0 landed (per wave), then barrier
    __builtin_amdgcn_s_barrier();

// Per K-tile: P0 {ds_read A-low + B, stage A(kt+3), bar, lgkm0, 16 MFMA, bar}
//             P1 {ds_read A-high,    stage B(kt+3), bar, lgkm0, 16 MFMA, gate, bar}
// Gate before the final barrier ensures tile kt+1 landed in EVERY wave before
// any wave reads it (vmcnt is per-wave; barrier publishes the guarantee).
#define KTILE(KT, DO_STAGE, GATESTR) do {                                   \
    const int cb_ = (KT) & 3;                                               \
    const bf16* Ab_ = smem + cb_ * (2 * BM * BK);                           \
    const bf16* Bb_ = Ab_ + BM * BK;                                        \
    bf16x8 aF[4], bF[4];                                                    \
    _Pragma("unroll")                                                       \
    for (int m_ = 0; m_ < 4; ++m_)                                          \
      aF[m_] = *(const bf16x8*)&Ab_[(wr + m_ * 16 + l15) * BK + kg * 8];    \
    _Pragma("unroll")                                                       \
    for (int n_ = 0; n_ < 4; ++n_)                                          \
      bF[n_] = *(const bf16x8*)&Bb_[(wc + n_ * 16 + l15) * BK + kg * 8];    \
    if (DO_STAGE) STAGE_A((KT) + 3, ((KT) + 3) & 3);                        \
    __builtin_amdgcn_s_barrier();                                           \
    asm volatile("s_waitcnt lgkmcnt(0)");                                   \
    __builtin_amdgcn_s_setprio(1);                                          \
    _Pragma("unroll")                                                       \
    for (int m_ = 0; m_ < 4; ++m_)                                          \
      _Pragma("unroll")                                                     \
      for (int n_ = 0; n_ < 4; ++n_)                                        \
        acc[m_][n_] = __builtin_amdgcn_mfma_f32_16x16x32_bf16(              \
            aF[m_], bF[n_], acc[m_][n_], 0, 0, 0);                          \
    __builtin_amdgcn_s_setprio(0);                                          \
    __builtin_amdgcn_s_barrier();                                           \
    _Pragma("unroll")                                                       \
    for (int m_ = 0; m_ < 4; ++m_)                                          \
      aF[m_] = *(const bf16x8*)&Ab_[(wr + 64 + m_ * 16 + l15) * BK + kg * 8]; \
    if (DO_STAGE) STAGE_B((KT) + 3, ((KT) + 3) & 3);                        \
    __builtin_amdgcn_s_barrier();                                           \
    asm volatile("s_waitcnt lgkmcnt(0)");                                   \
    __builtin_amdgcn_s_setprio(1);                                          \
    _Pragma("unroll")                                                       \
    for (int m_ = 0; m_ < 4; ++m_)                                          \
      _Pragma("unroll")                                                     \
      for (int n_ = 0; n_ < 4; ++n_)                                        \
        acc[4 + m_][n_] = __builtin_amdgcn_mfma_f32_16x16x32_bf16(          \
            aF[m_], bF[n_], acc[4 + m_][n_], 0, 0, 0);                      \
    __builtin_amdgcn_s_setprio(0);                                          \
    asm volatile("s_waitcnt " GATESTR ::: "memory");                        \
    __builtin_amdgcn_s_barrier();                                           \
  } while (0)

    // main loop: 64 K-tiles; stage kt+3 while computing kt (3 tiles in flight)
    for (int kt = 0; kt < 61; ++kt) KTILE(kt, true, "vmcnt(8)");
    KTILE(61, false, "vmcnt(4)");   // tail: drain 8 -> 4 -> 0
    KTILE(62, false, "vmcnt(0)");
    KTILE(63, false, "vmcnt(0)");

#undef KTILE
#undef STAGE_A
#undef STAGE_B

    // ---- epilogue: masked C-write (mask only matters for split-expert tiles)
    int rlo = offs[e] - mrow;     if (rlo < 0)  rlo = 0;
    int rhi = offs[e + 1] - mrow; if (rhi > BM) rhi = BM;
    #pragma unroll
    for (int i = 0; i < 8; ++i) {
      const int rb = wr + (i >> 2) * 64 + (i & 3) * 16 + kg * 4;
      #pragma unroll
      for (int j = 0; j < 4; ++j) {
        const int r = rb + j;
        if (r >= rlo && r < rhi) {
          #pragma unroll
          for (int n = 0; n < 4; ++n)
            Cb[(size_t)r * DOUT + wc + n * 16 + l15] = acc[i][n][j];
        }
      }
    }
  }
}

// ---------------- fallback (ws too small): fp32 tiled GEMM ----------------
__device__ __forceinline__ int find_expert_fb(const void* esv, int mrow) {
  const int* p32 = (const int*)esv;
  const long long* p64 = (const long long*)esv;
  bool is64 = (p32[1] == 0);
  long long cum = 0; int e = 0;
  #pragma unroll
  for (int i = 0; i < NE; ++i) {
    long long s = is64 ? p64[i] : (long long)p32[i];
    long long nx = cum + s;
    if ((long long)mrow >= nx) e = i + 1;
    cum = nx;
  }
  return e;
}

__global__ __launch_bounds__(256) void fallback_gemm(
    const float* __restrict__ A, const float* __restrict__ W,
    const void* __restrict__ es, float* __restrict__ C) {
  __shared__ float As[64][17];
  __shared__ float Bs[16][65];
  const int bid = blockIdx.x;
  const int mtile = bid >> 7;
  const int ntile = bid & 127;
  const int mrow = mtile * 64, ncol = ntile * 64;
  const int e = find_expert_fb(es, mrow);
  const int t = threadIdx.x;
  const int tx = t & 15, ty = t >> 4;
  float acc[4][4] = {};
  const float* Ab = A + (size_t)mrow * DIN;
  const float* Wb = W + (size_t)e * DIN * DOUT + ncol;
  for (int kb = 0; kb < DIN; kb += 16) {
    {
      const int r = t >> 2, c = (t & 3) * 4;
      float4 v = *(const float4*)(Ab + (size_t)r * DIN + kb + c);
      const float* f = (const float*)&v;
      #pragma unroll
      for (int j = 0; j < 4; ++j) As[r][c + j] = f[j];
      const int r2 = t >> 4, c2 = (t & 15) * 4;
      float4 wv = *(const float4*)(Wb + (size_t)(kb + r2) * DOUT + c2);
      const float* g = (const float*)&wv;
      #pragma unroll
      for (int j = 0; j < 4; ++j) Bs[r2][c2 + j] = g[j];
    }
    __syncthreads();
    #pragma unroll
    for (int k = 0; k < 16; ++k)
      #pragma unroll
      for (int i = 0; i < 4; ++i)
        #pragma unroll
        for (int j = 0; j < 4; ++j)
          acc[i][j] += As[ty * 4 + i][k] * Bs[k][tx * 4 + j];
    __syncthreads();
  }
  #pragma unroll
  for (int i = 0; i < 4; ++i)
    #pragma unroll
    for (int j = 0; j < 4; ++j)
      C[(size_t)(mrow + ty * 4 + i) * DOUT + ncol + tx * 4 + j] = acc[i][j];
}

extern "C" void kernel_launch(void* const* d_in, const int* in_sizes, int n_in,
                              void* d_out, int out_size, void* d_ws, size_t ws_size,
                              hipStream_t stream) {
  const float* A = (const float*)d_in[0];
  const float* W = (const float*)d_in[1];
  const void*  es = (const void*)d_in[2];
  float* C = (float*)d_out;

  const size_t needA = (size_t)NTOK * DIN * sizeof(bf16);        // 32 MB
  const size_t needB = (size_t)NE * DIN * DOUT * sizeof(bf16);   // 256 MB

  if (ws_size >= needA + needB) {
    bf16* Ab = (bf16*)d_ws;
    bf16* BT = (bf16*)((char*)d_ws + needA);
    convertA<<<(NTOK * DIN) / (256 * 8), 256, 0, stream>>>(A, Ab);
    dim3 gB(DOUT / 64, DIN / 64, NE);
    convertB<<<gB, 256, 0, stream>>>(W, BT);
    grouped_gemm<<<(NTOK / BM) * (DOUT / BN), TPB, 0, stream>>>(Ab, BT, es, C);
  } else {
    fallback_gemm<<<(NTOK / 64) * (DOUT / 64), 256, 0, stream>>>(A, W, es, C);
  }
}